// Round 1
// baseline (108.981 us; speedup 1.0000x reference)
//
#include <hip/hip_runtime.h>
#include <math.h>

// out[b,s,e] = sum_q cos(x[b,s,q] + theta[q]) * W[e,q]
// B=4, S=4096, E=1024, Q=8  -> tokens = 16384
// Memory-bound on the 67 MB output write; floor ~11 us at 6.3 TB/s.

#define E_DIM 1024
#define Q_DIM 8
#define TPB 256
#define TOK_PER_BLOCK 16

__global__ __launch_bounds__(TPB) void quantum_proj_kernel(
    const float* __restrict__ x,      // [tokens, 1024]
    const float* __restrict__ theta,  // [8]
    const float* __restrict__ W,      // [1024, 8]
    float* __restrict__ out,          // [tokens, 1024]
    int tokens)
{
    __shared__ float P[TOK_PER_BLOCK * Q_DIM];   // 512 B

    const int t    = threadIdx.x;
    const int tok0 = blockIdx.x * TOK_PER_BLOCK;

    // ---- Phase 1: threads 0..127 compute cos(x[tok][q] + theta[q]) into LDS
    if (t < TOK_PER_BLOCK * Q_DIM) {
        const int tl = t >> 3;    // local token
        const int q  = t & 7;
        const int tok = tok0 + tl;
        float v = 0.0f;
        if (tok < tokens) {
            v = cosf(x[(size_t)tok * E_DIM + q] + theta[q]);
        }
        P[t] = v;
    }

    // ---- Load this thread's 4 W rows (e = 4t .. 4t+3), 32 contiguous floats.
    // W row e is 8 contiguous floats = 2 float4; thread t reads bytes [128t, 128t+128).
    const int e0 = t * 4;
    float w[4][Q_DIM];
    {
        const float4* W4 = (const float4*)W;
        #pragma unroll
        for (int i = 0; i < 4; ++i) {
            float4 a = W4[(size_t)(e0 + i) * 2 + 0];
            float4 b = W4[(size_t)(e0 + i) * 2 + 1];
            w[i][0] = a.x; w[i][1] = a.y; w[i][2] = a.z; w[i][3] = a.w;
            w[i][4] = b.x; w[i][5] = b.y; w[i][6] = b.z; w[i][7] = b.w;
        }
    }

    __syncthreads();

    // ---- Phase 2: per token, 32 FMAs + one float4 store (coalesced 4 KB/token/block)
    #pragma unroll
    for (int tl = 0; tl < TOK_PER_BLOCK; ++tl) {
        const int tok = tok0 + tl;
        if (tok >= tokens) break;

        float p[Q_DIM];
        #pragma unroll
        for (int q = 0; q < Q_DIM; ++q) p[q] = P[tl * Q_DIM + q];  // LDS broadcast

        float acc[4] = {0.f, 0.f, 0.f, 0.f};
        #pragma unroll
        for (int i = 0; i < 4; ++i) {
            #pragma unroll
            for (int q = 0; q < Q_DIM; ++q) {
                acc[i] = fmaf(p[q], w[i][q], acc[i]);
            }
        }

        float4* op = (float4*)(out + (size_t)tok * E_DIM);
        op[t] = make_float4(acc[0], acc[1], acc[2], acc[3]);
    }
}

extern "C" void kernel_launch(void* const* d_in, const int* in_sizes, int n_in,
                              void* d_out, int out_size, void* d_ws, size_t ws_size,
                              hipStream_t stream) {
    const float* x     = (const float*)d_in[0];
    const float* theta = (const float*)d_in[1];
    const float* W     = (const float*)d_in[2];
    float* out = (float*)d_out;

    const int tokens = in_sizes[0] / E_DIM;            // 16384
    const int grid   = (tokens + TOK_PER_BLOCK - 1) / TOK_PER_BLOCK;  // 1024

    quantum_proj_kernel<<<dim3(grid), dim3(TPB), 0, stream>>>(x, theta, W, out, tokens);
}